// Round 5
// baseline (448.044 us; speedup 1.0000x reference)
//
#include <hip/hip_runtime.h>

#define NBATCH 4
#define NPTS   16384
#define NQ     4096
#define NCH    64
#define K      32
#define CHOUT  67   // 3 + NCH

typedef float v2f __attribute__((ext_vector_type(2)));
typedef float v4f __attribute__((ext_vector_type(4)));
typedef int   v4i __attribute__((ext_vector_type(4)));

// Packed fp32 ops via asm: exact rn rounding, no contraction possible.
__device__ __forceinline__ v2f pk_add(v2f a, v2f b) {
    v2f d; asm("v_pk_add_f32 %0, %1, %2" : "=v"(d) : "v"(a), "v"(b)); return d;
}
__device__ __forceinline__ v2f pk_mul(v2f a, v2f b) {
    v2f d; asm("v_pk_mul_f32 %0, %1, %2" : "=v"(d) : "v"(a), "v"(b)); return d;
}
// FMA variant: used ONLY in pass 1 (threshold estimate), never for the exact
// pass-2 distances that determine selection/ordering.
__device__ __forceinline__ v2f pk_fma(v2f a, v2f b, v2f c) {
    v2f d; asm("v_pk_fma_f32 %0, %1, %2, %3" : "=v"(d) : "v"(a), "v"(b), "v"(c)); return d;
}
// Whole-wave shift lane i -> i+1 (DPP wave_shr:1, ctrl 0x138). Lane 0 keeps old.
__device__ __forceinline__ int dpp_shr1(int v) {
    return __builtin_amdgcn_update_dpp(v, v, 0x138, 0xf, 0xf, false);
}
// Per-lane select on an arbitrary 64-bit lane mask held in SGPRs: m ? t : f.
__device__ __forceinline__ int sel_mask_i(unsigned long long m, int t, int f) {
    int d; asm("v_cndmask_b32 %0, %2, %1, %3" : "=v"(d) : "v"(t), "v"(f), "s"(m));
    return d;
}

// ---------------------------------------------------------------------------
// R11: ONE dispatch. Three different secondary kernels all measured ~115-130us
// regardless of implementation -> per-launch/serialization cost, not kernel
// cost. Fold the feature transpose into the knn kernel:
//  - 1024 blocks == 1024 64x64 transpose tiles. Block start: steal one tile
//    (atomic counter), transpose via 16-KB swizzled LDS view, release via
//    __threadfence + done++.
//  - Before the fused featT gather (~170us later): wait done==1024 with a
//    WORK-STEALING spin (a waiting block executes leftover tiles itself) ->
//    no dependence on dispatch order or co-residency; acquire fence before
//    reading featT (cross-XCD L2).
// knn main loop / selection: bit-identical to the verified R9 (176us) kernel.
// ---------------------------------------------------------------------------
constexpr int TILE = 1024;          // points per tile
constexpr int NT   = NPTS / TILE;   // 16 tiles per pass
constexpr int QPW  = 4;
constexpr int QPB  = 16;            // 4 waves x QPW
constexpr int TTILES = NBATCH * (NPTS / 64);   // 1024 transpose tiles

#define VW3 asm volatile("s_waitcnt vmcnt(3)" ::: "memory")
#define VW0 asm volatile("s_waitcnt vmcnt(0)" ::: "memory")
#define BAR __builtin_amdgcn_s_barrier()

// Transpose one 64n x 64c tile of features (B,C,N) -> featT (B,N,C).
// sm is a [64][64] float view (16 KB). Swizzle col' = col ^ (((n>>2)&15)<<2):
// store side 2 lanes/bank (free), read side conflict-free, v4f both sides.
__device__ __forceinline__ void do_tile(const float* __restrict__ f,
                                        float* __restrict__ ft,
                                        int t, int tid, float (*sm)[64]) {
    const int nb = t & 255;
    const int b  = t >> 8;
    const int n0 = nb * 64;
    const int w = tid >> 6, lane = tid & 63;
    const int r = lane >> 4, i = lane & 15;
    const float* fb = f + (size_t)b * NCH * NPTS;
#pragma unroll
    for (int g = 0; g < 4; ++g) {
        const int c = g * 16 + w * 4 + r;
        const v4f v = *(const v4f*)(fb + (size_t)c * NPTS + n0 + 4 * i);
        const int cs = c ^ (i << 2);     // n = 4i+e -> (n>>2)&15 == i
        sm[4 * i + 0][cs] = v.x;
        sm[4 * i + 1][cs] = v.y;
        sm[4 * i + 2][cs] = v.z;
        sm[4 * i + 3][cs] = v.w;
    }
    __syncthreads();
    float* ftb = ft + ((size_t)b * NPTS + n0) * NCH;
#pragma unroll
    for (int h = 0; h < 4; ++h) {
        const int n = h * 16 + w * 4 + r;
        const int cs = (4 * i) ^ (((n >> 2) & 15) << 2);
        const v4f v = *(const v4f*)(&sm[n][cs]);
        *(v4f*)(ftb + (size_t)n * NCH + 4 * i) = v;
    }
}

template <bool FUSED>
__global__ __launch_bounds__(256) void knn_kernel(
    const float* __restrict__ xyz,
    const float* __restrict__ new_xyz,
    const float* __restrict__ features,  // original (B,C,N); FUSED only
    float* __restrict__ ft,              // featT (B,N,C) in ws; FUSED only
    int*   __restrict__ ctr,             // [steal, done] in ws; FUSED only
    int*   __restrict__ out_idx,         // !FUSED only
    float* __restrict__ out)
{
    // 3 ring buffers, raw AoS copy of a 1024-point tile (12288 B each).
    __shared__ __align__(16) float sb[3][TILE * 3];   // 36 KB
    __shared__ int s_comm;

    const int tid  = threadIdx.x;
    const int lane = tid & 63;
    const int wave = tid >> 6;
    const int b    = blockIdx.x >> 8;                  // 256 blocks per batch
    const int q0   = (blockIdx.x & 255) * QPB + wave * QPW;

    // ---- integrated transpose: take one tile before knn staging begins ----
    if (FUSED) {
        if (tid == 0) s_comm = atomicAdd(&ctr[0], 1);
        __syncthreads();
        const int t2 = s_comm;
        if (t2 < TTILES) {
            do_tile(features, ft, t2, tid, (float(*)[64])&sb[0][0]);
            __syncthreads();                 // drains all global stores (vmcnt 0)
            if (tid == 0) { __threadfence(); atomicAdd(&ctr[1], 1); }
        }
    }

    const float* xb = xyz + (size_t)b * NPTS * 3;
    // Per-lane global byte address for staging: wave w copies tile bytes
    // [w*3072, w*3072+3072) as 3 chunks of 64 lanes x 16 B.
    const char* gbase = (const char*)xb + wave * 3072 + lane * 16;

    // offset=0 ONLY (global_load_lds applies imm offset to BOTH addresses).
    auto STAGE = [&](int buf, int t0) {
        const char* g = gbase + (size_t)t0 * 12;
        char* l = (char*)(&sb[buf][0]) + wave * 3072;
#define GLL(k) __builtin_amdgcn_global_load_lds( \
        (const __attribute__((address_space(1))) unsigned int*)(g + (k) * 1024), \
        (__attribute__((address_space(3))) unsigned int*)(l + (k) * 1024), \
        16, 0, 0)
        GLL(0); GLL(1); GLL(2);
#undef GLL
    };

    // Negated query coords (wave-uniform -> SGPR) + packed VGPR broadcasts.
    float nqx[QPW], nqy[QPW], nqz[QPW];
    v2f nqx2[QPW], nqy2[QPW], nqz2[QPW];
#pragma unroll
    for (int j = 0; j < QPW; ++j) {
        const int base = ((b * NQ) + q0 + j) * 3;
        nqx[j] = __int_as_float(__builtin_amdgcn_readfirstlane(__float_as_int(-new_xyz[base + 0])));
        nqy[j] = __int_as_float(__builtin_amdgcn_readfirstlane(__float_as_int(-new_xyz[base + 1])));
        nqz[j] = __int_as_float(__builtin_amdgcn_readfirstlane(__float_as_int(-new_xyz[base + 2])));
        nqx2[j] = (v2f){nqx[j], nqx[j]};
        nqy2[j] = (v2f){nqy[j], nqy[j]};
        nqz2[j] = (v2f){nqz[j], nqz[j]};
    }

    const float INF  = __int_as_float(0x7f800000);
    const float NINF = __int_as_float(0xff800000);

    // ---------------- Pass 1: per-lane running minima (FMA ok) --------------
    float vmA[QPW], vmB[QPW];
#pragma unroll
    for (int j = 0; j < QPW; ++j) { vmA[j] = INF; vmB[j] = INF; }

    STAGE(0, 0);
    STAGE(1, TILE);
    VW3; BAR;                       // own tile-0 writes done + all waves' too
    {
        int cur = 0, pre = 2;
        for (int t = 0; t < NT; ++t) {
            if (t + 2 < NT) STAGE(pre, (t + 2) * TILE);
            const float* sp = &sb[cur][0];
#pragma unroll
            for (int ii = 0; ii < TILE / 128; ++ii) {
                // lane handles points (ii*128+lane, ii*128+lane+64)
                const float* qp = sp + 3 * (ii * 128 + lane);
                const v2f px2 = {qp[0], qp[192]};   // ds_read2_b32 pairs
                const v2f py2 = {qp[1], qp[193]};
                const v2f pz2 = {qp[2], qp[194]};
#pragma unroll
                for (int j = 0; j < QPW; ++j) {
                    const v2f dx = pk_add(px2, nqx2[j]);
                    const v2f dy = pk_add(py2, nqy2[j]);
                    const v2f dz = pk_add(pz2, nqz2[j]);
                    const v2f d2 = pk_fma(dx, dx, pk_fma(dy, dy, pk_mul(dz, dz)));
                    vmA[j] = fminf(vmA[j], d2.x);
                    vmB[j] = fminf(vmB[j], d2.y);
                }
            }
            if (t + 1 < NT) {
                if (t + 2 < NT) { VW3; } else { VW0; }
                BAR;                // tile t+1 visible to all waves
            }
            cur = (cur == 2) ? 0 : cur + 1;
            pre = (pre == 2) ? 0 : pre + 1;
        }
    }
    BAR;   // all waves done reading sb before pass-2 prologue overwrites it

    // Pass-2 prologue staging overlaps the radix descent.
    STAGE(0, 0);
    STAGE(1, TILE);

    // ---------------- T' = exact 32nd smallest of 64 lane minima -----------
    // Lane minima used FMA; +64 ulps keeps T' a provable upper bound on the
    // exact-rn 32nd distance (rel. slack 3.8e-6 >> fma-vs-rn few-ulp error).
    float Tf[QPW];
#pragma unroll
    for (int j = 0; j < QPW; ++j) {
        const unsigned u = __float_as_uint(fminf(vmA[j], vmB[j]));
        unsigned t = 0x7fffffffu;                       // > all finite bits
        for (int bb = 30; bb >= 0; --bb) {              // uniform radix descent
            const unsigned tt = t ^ (1u << bb);
            const int cnt = __popcll(__ballot(u <= tt));
            if (cnt >= 32) t = tt;                      // s_cselect, branchless
        }
        Tf[j] = __uint_as_float(t + 64);
    }

    // ---------------- Pass 2: filtered exact selection (rn-exact) ----------
    float ld[QPW]; int li[QPW];
#pragma unroll
    for (int j = 0; j < QPW; ++j) {
        ld[j] = (lane < K) ? INF : NINF;   // -inf sentinel: lanes 32+ never shift
        li[j] = 0;
    }

    VW3; BAR;                       // pass-2 tile 0 landed
    {
        int cur = 0, pre = 2;
        for (int t = 0; t < NT; ++t) {
            if (t + 2 < NT) STAGE(pre, (t + 2) * TILE);
            const int t0 = t * TILE;
            const float* sp = &sb[cur][0];
#pragma unroll
            for (int ii = 0; ii < TILE / 128; ++ii) {
                const int gb = t0 + ii * 128;              // wave-uniform
                const float* qp = sp + 3 * (ii * 128 + lane);
                const v2f px2 = {qp[0], qp[192]};
                const v2f py2 = {qp[1], qp[193]};
                const v2f pz2 = {qp[2], qp[194]};
#pragma unroll
                for (int j = 0; j < QPW; ++j) {
                    const v2f dx = pk_add(px2, nqx2[j]);
                    const v2f dy = pk_add(py2, nqy2[j]);
                    const v2f dz = pk_add(pz2, nqz2[j]);
                    const v2f d2 = pk_add(pk_add(pk_mul(dx, dx), pk_mul(dy, dy)),
                                          pk_mul(dz, dz));
                    unsigned long long m0 = __ballot(d2.x <= Tf[j]);
                    unsigned long long m1 = __ballot(d2.y <= Tf[j]);
                    // all m0 candidates (gb+c) < all m1 candidates (gb+64+c):
                    // popping m0 to exhaustion first keeps global ascending order.
                    while (m0 | m1) {
                        const bool lo = (m0 != 0);
                        const unsigned long long mm = lo ? m0 : m1;
                        const int c = (int)__builtin_ctzll(mm);
                        if (lo) m0 &= m0 - 1; else m1 &= m1 - 1;
                        const int b0 = __builtin_amdgcn_readlane(__float_as_int(d2.x), c);
                        const int b1 = __builtin_amdgcn_readlane(__float_as_int(d2.y), c);
                        const float dn = __int_as_float(lo ? b0 : b1);
                        const int cand = gb + (lo ? 0 : 64) + c;
                        // Self-guarding sorted insert (no-op if dn >= current max).
                        const unsigned long long sh = __ballot(ld[j] > dn);
                        const int p = sh ? (int)__builtin_ctzll(sh) : 64;
                        const int sld = dpp_shr1(__float_as_int(ld[j]));
                        const int sli = dpp_shr1(li[j]);
                        const int nld = sel_mask_i(sh, sld, __float_as_int(ld[j]));
                        const int nli = sel_mask_i(sh, sli, li[j]);
                        ld[j] = __int_as_float((lane == p) ? __float_as_int(dn) : nld);
                        li[j] = (lane == p) ? cand : nli;
                    }
                }
            }
            if (t + 1 < NT) {
                if (t + 2 < NT) { VW3; } else { VW0; }
                BAR;
            }
            cur = (cur == 2) ? 0 : cur + 1;
            pre = (pre == 2) ? 0 : pre + 1;
        }
    }

    // ---------------- Epilogue ----------------
    const size_t plane = (size_t)NQ * K;
    // centered xyz channels 0..2 first (independent of featT)
#pragma unroll
    for (int j = 0; j < QPW; ++j) {
        const int q = q0 + j;
        if (lane < K) {
            const int idx = li[j];
            const float px = xb[idx * 3 + 0];
            const float py = xb[idx * 3 + 1];
            const float pz = xb[idx * 3 + 2];
            const size_t o = (((size_t)b * CHOUT + 0) * NQ + q) * K + lane;
            out[o]             = __fadd_rn(px, nqx[j]);   // == px - qx, exact
            out[o + plane]     = __fadd_rn(py, nqy[j]);
            out[o + 2 * plane] = __fadd_rn(pz, nqz[j]);
        }
        if (!FUSED && lane < K) {
            out_idx[((size_t)(b * NQ) + q) * K + lane] = li[j];
        }
    }

    if (FUSED) {
        // ---- wait for all transpose tiles: work-stealing spin (deadlock-
        // free: a waiting block executes leftover tiles itself). ----
        for (;;) {
            if (tid == 0) {
                const int d = __hip_atomic_load(&ctr[1], __ATOMIC_RELAXED,
                                                __HIP_MEMORY_SCOPE_AGENT);
                s_comm = (d >= TTILES) ? -1 : atomicAdd(&ctr[0], 1);
            }
            __syncthreads();
            const int t2 = s_comm;
            if (t2 < 0) break;
            if (t2 < TTILES) {
                do_tile(features, ft, t2, tid, (float(*)[64])&sb[0][0]);
                __syncthreads();
                if (tid == 0) { __threadfence(); atomicAdd(&ctr[1], 1); }
            } else {
                __builtin_amdgcn_s_sleep(8);
            }
            __syncthreads();
        }
        __threadfence();   // acquire: invalidate local L2 before featT reads

        // feature channels 3..66: lane (s,h) pulls half-row h (128 B) of
        // point li[j]@lane s, scatters per-channel (2x128-B chunks/instr).
#pragma unroll
        for (int j = 0; j < QPW; ++j) {
            const int q = q0 + j;
            const int s = lane & 31, h = lane >> 5;
            const int pidx = __shfl(li[j], s);
            const v4f* src = (const v4f*)(ft + ((size_t)b * NPTS + pidx) * NCH) + h * 8;
            v4f r[8];
#pragma unroll
            for (int k2 = 0; k2 < 8; ++k2) r[k2] = src[k2];
            float* ob = out + (((size_t)b * CHOUT + 3) * NQ + q) * K + s;
#pragma unroll
            for (int k2 = 0; k2 < 8; ++k2) {
                const int c0 = h * 32 + k2 * 4;
                ob[(size_t)(c0 + 0) * plane] = r[k2].x;
                ob[(size_t)(c0 + 1) * plane] = r[k2].y;
                ob[(size_t)(c0 + 2) * plane] = r[k2].z;
                ob[(size_t)(c0 + 3) * plane] = r[k2].w;
            }
        }
    }
}

// ---------------------------------------------------------------------------
// Fallback gather (R6 path) in case ws_size cannot hold featT + counters.
// ---------------------------------------------------------------------------
__global__ __launch_bounds__(1024) void gather_kernel(
    const float* __restrict__ features,
    const int*   __restrict__ idx,
    float* __restrict__ out)
{
    __shared__ __align__(16) float row[NPTS];   // 64 KB

    const int tid  = threadIdx.x;
    const int half = blockIdx.x & 1;
    const int c    = (blockIdx.x >> 1) & 63;
    const int b    = blockIdx.x >> 7;

    const v4f* src = (const v4f*)(features + ((size_t)(b * NCH + c)) * NPTS);
    for (int k2 = tid; k2 < NPTS / 4; k2 += 1024) ((v4f*)row)[k2] = src[k2];
    __syncthreads();

    const size_t hofs = (size_t)half * (NQ * K / 2);
    const v4i* gi = (const v4i*)(idx + (size_t)b * NQ * K + hofs);
    v4f* dst = (v4f*)(out + ((size_t)(b * CHOUT + 3 + c)) * NQ * K + hofs);

    v4i cur = gi[tid];
#pragma unroll
    for (int it = 0; it < 16; ++it) {                  // NQ*K/8/1024 = 16
        v4i nxt;
        if (it < 15) nxt = gi[tid + (it + 1) * 1024];
        v4f o;
        o.x = row[cur.x]; o.y = row[cur.y]; o.z = row[cur.z]; o.w = row[cur.w];
        dst[tid + it * 1024] = o;
        cur = nxt;
    }
}

extern "C" void kernel_launch(void* const* d_in, const int* in_sizes, int n_in,
                              void* d_out, int out_size, void* d_ws, size_t ws_size,
                              hipStream_t stream) {
    const float* xyz      = (const float*)d_in[0];
    const float* new_xyz  = (const float*)d_in[1];
    const float* features = (const float*)d_in[2];
    float* out = (float*)d_out;

    const size_t ft_bytes  = (size_t)NBATCH * NPTS * NCH * sizeof(float);  // 16.8 MB
    const size_t idx_bytes = (size_t)NBATCH * NQ * K * sizeof(int);        // 2 MB

    if (ws_size >= ft_bytes + 16) {
        float* featT = (float*)d_ws;
        int*   ctr   = (int*)((char*)d_ws + ft_bytes);   // [steal, done]
        hipMemsetAsync(ctr, 0, 8, stream);
        knn_kernel<true><<<dim3(NBATCH * (NQ / QPB)), dim3(256), 0, stream>>>(
            xyz, new_xyz, features, featT, ctr, nullptr, out);
    } else {
        int* ws_idx = (int*)d_ws;   // 2 MB
        knn_kernel<false><<<dim3(NBATCH * (NQ / QPB)), dim3(256), 0, stream>>>(
            xyz, new_xyz, nullptr, nullptr, nullptr, ws_idx, out);
        gather_kernel<<<dim3(NBATCH * NCH * 2), dim3(1024), 0, stream>>>(features, ws_idx, out);
    }
}

// Round 6
// 297.080 us; speedup vs baseline: 1.5082x; 1.5082x over previous
//
#include <hip/hip_runtime.h>

#define NBATCH 4
#define NPTS   16384
#define NQ     4096
#define NCH    64
#define K      32
#define CHOUT  67   // 3 + NCH

typedef float v2f __attribute__((ext_vector_type(2)));
typedef float v4f __attribute__((ext_vector_type(4)));
typedef int   v4i __attribute__((ext_vector_type(4)));

// Packed fp32 ops via asm: exact rn rounding, no contraction possible.
__device__ __forceinline__ v2f pk_add(v2f a, v2f b) {
    v2f d; asm("v_pk_add_f32 %0, %1, %2" : "=v"(d) : "v"(a), "v"(b)); return d;
}
__device__ __forceinline__ v2f pk_mul(v2f a, v2f b) {
    v2f d; asm("v_pk_mul_f32 %0, %1, %2" : "=v"(d) : "v"(a), "v"(b)); return d;
}
// FMA variant: used ONLY in pass 1 (threshold estimate), never for the exact
// pass-2 distances that determine selection/ordering.
__device__ __forceinline__ v2f pk_fma(v2f a, v2f b, v2f c) {
    v2f d; asm("v_pk_fma_f32 %0, %1, %2, %3" : "=v"(d) : "v"(a), "v"(b), "v"(c)); return d;
}
// Whole-wave shift lane i -> i+1 (DPP wave_shr:1, ctrl 0x138). Lane 0 keeps old.
__device__ __forceinline__ int dpp_shr1(int v) {
    return __builtin_amdgcn_update_dpp(v, v, 0x138, 0xf, 0xf, false);
}
// Per-lane select on an arbitrary 64-bit lane mask held in SGPRs: m ? t : f.
__device__ __forceinline__ int sel_mask_i(unsigned long long m, int t, int f) {
    int d; asm("v_cndmask_b32 %0, %2, %1, %3" : "=v"(d) : "v"(t), "v"(f), "s"(m));
    return d;
}

// ---------------------------------------------------------------------------
// R12: R11 proved the ~110us total-vs-knn gap is HARNESS-fixed (persists with
// a single kernel) -> only knn matters. R9's knn (176us) stalls ~97us; theory:
// block-wide s_barrier convoying (4 waves align every tile-round; R10 showed
// elapsed tracks barrier granularity). Fix: SINGLE-WAVE blocks (64 thr),
// QPW=4 -> 4096 blocks, 16 WGs/CU (same 16 waves/CU as R9), each wave a
// private 9-KB ring-3 of 256-pt tiles paced ONLY by per-wave vmcnt(3):
// ZERO s_barrier in the kernel. Ballot/DPP/radix/insert already wave-level.
// Ring-slot reuse is wave-local-safe: all ds_reads of a slot are consumed
// (compiler lgkmcnt before use) before the overwriting STAGE issues in
// program order. Math/selection: bit-identical to verified R9.
// ---------------------------------------------------------------------------
constexpr int TILE = 256;           // points per tile (3072 B)
constexpr int NT   = NPTS / TILE;   // 64 tiles per pass
constexpr int QPW  = 4;

#define VW3 asm volatile("s_waitcnt vmcnt(3)" ::: "memory")
#define VW0 asm volatile("s_waitcnt vmcnt(0)" ::: "memory")

template <bool FUSED>
__global__ __launch_bounds__(64) void knn_kernel(
    const float* __restrict__ xyz,
    const float* __restrict__ new_xyz,
    const float* __restrict__ ft,     // featT (B,N,C); FUSED only
    int*   __restrict__ out_idx,      // !FUSED only
    float* __restrict__ out)
{
    // Private per-block(=per-wave) ring: 3 x 3072 B = 9216 B.
    __shared__ __align__(16) float sb[3][TILE * 3];

    const int lane = threadIdx.x;
    const int b    = blockIdx.x >> 10;                 // 1024 blocks per batch
    const int q0   = (blockIdx.x & 1023) * QPW;

    const float* xb = xyz + (size_t)b * NPTS * 3;
    const char* gbase = (const char*)xb + lane * 16;

    // Pure linear copy: one tile = 3 chunks of 64 lanes x 16 B. offset=0 ONLY
    // (global_load_lds applies its imm offset to BOTH global and LDS addrs).
    auto STAGE = [&](int buf, int t0) {
        const char* g = gbase + (size_t)t0 * 12;
        char* l = (char*)(&sb[buf][0]);
#define GLL(k) __builtin_amdgcn_global_load_lds( \
        (const __attribute__((address_space(1))) unsigned int*)(g + (k) * 1024), \
        (__attribute__((address_space(3))) unsigned int*)(l + (k) * 1024), \
        16, 0, 0)
        GLL(0); GLL(1); GLL(2);
#undef GLL
    };

    // Negated query coords (wave-uniform -> SGPR) + packed VGPR broadcasts.
    float nqx[QPW], nqy[QPW], nqz[QPW];
    v2f nqx2[QPW], nqy2[QPW], nqz2[QPW];
#pragma unroll
    for (int j = 0; j < QPW; ++j) {
        const int base = ((b * NQ) + q0 + j) * 3;
        nqx[j] = __int_as_float(__builtin_amdgcn_readfirstlane(__float_as_int(-new_xyz[base + 0])));
        nqy[j] = __int_as_float(__builtin_amdgcn_readfirstlane(__float_as_int(-new_xyz[base + 1])));
        nqz[j] = __int_as_float(__builtin_amdgcn_readfirstlane(__float_as_int(-new_xyz[base + 2])));
        nqx2[j] = (v2f){nqx[j], nqx[j]};
        nqy2[j] = (v2f){nqy[j], nqy[j]};
        nqz2[j] = (v2f){nqz[j], nqz[j]};
    }

    const float INF  = __int_as_float(0x7f800000);
    const float NINF = __int_as_float(0xff800000);

    // ---------------- Pass 1: per-lane running minima (FMA ok) --------------
    float vmA[QPW], vmB[QPW];
#pragma unroll
    for (int j = 0; j < QPW; ++j) { vmA[j] = INF; vmB[j] = INF; }

    STAGE(0, 0);
    STAGE(1, TILE);
    VW3;                            // tile 0's 3 loads landed (wave-local)
    {
        int cur = 0, pre = 2;
        for (int t = 0; t < NT; ++t) {
            if (t + 2 < NT) STAGE(pre, (t + 2) * TILE);
            const float* sp = &sb[cur][0];
#pragma unroll
            for (int ii = 0; ii < TILE / 128; ++ii) {
                // lane handles points (ii*128+lane, ii*128+lane+64)
                const float* qp = sp + 3 * (ii * 128 + lane);
                const v2f px2 = {qp[0], qp[192]};   // ds_read2_b32 pairs
                const v2f py2 = {qp[1], qp[193]};
                const v2f pz2 = {qp[2], qp[194]};
#pragma unroll
                for (int j = 0; j < QPW; ++j) {
                    const v2f dx = pk_add(px2, nqx2[j]);
                    const v2f dy = pk_add(py2, nqy2[j]);
                    const v2f dz = pk_add(pz2, nqz2[j]);
                    const v2f d2 = pk_fma(dx, dx, pk_fma(dy, dy, pk_mul(dz, dz)));
                    vmA[j] = fminf(vmA[j], d2.x);
                    vmB[j] = fminf(vmB[j], d2.y);
                }
            }
            if (t + 1 < NT) {
                if (t + 2 < NT) { VW3; } else { VW0; }
            }
            cur = (cur == 2) ? 0 : cur + 1;
            pre = (pre == 2) ? 0 : pre + 1;
        }
    }

    // Pass-2 prologue staging overlaps the radix descent (wave-local only).
    STAGE(0, 0);
    STAGE(1, TILE);

    // ---------------- T' = exact 32nd smallest of 64 lane minima -----------
    // Lane minima used FMA; +64 ulps keeps T' a provable upper bound on the
    // exact-rn 32nd distance (rel. slack 3.8e-6 >> fma-vs-rn few-ulp error).
    float Tf[QPW];
#pragma unroll
    for (int j = 0; j < QPW; ++j) {
        const unsigned u = __float_as_uint(fminf(vmA[j], vmB[j]));
        unsigned t = 0x7fffffffu;                       // > all finite bits
        for (int bb = 30; bb >= 0; --bb) {              // uniform radix descent
            const unsigned tt = t ^ (1u << bb);
            const int cnt = __popcll(__ballot(u <= tt));
            if (cnt >= 32) t = tt;                      // s_cselect, branchless
        }
        Tf[j] = __uint_as_float(t + 64);
    }

    // ---------------- Pass 2: filtered exact selection (rn-exact) ----------
    float ld[QPW]; int li[QPW];
#pragma unroll
    for (int j = 0; j < QPW; ++j) {
        ld[j] = (lane < K) ? INF : NINF;   // -inf sentinel: lanes 32+ never shift
        li[j] = 0;
    }

    VW3;                            // pass-2 tile 0 landed
    {
        int cur = 0, pre = 2;
        for (int t = 0; t < NT; ++t) {
            if (t + 2 < NT) STAGE(pre, (t + 2) * TILE);
            const int t0 = t * TILE;
            const float* sp = &sb[cur][0];
#pragma unroll
            for (int ii = 0; ii < TILE / 128; ++ii) {
                const int gb = t0 + ii * 128;              // wave-uniform
                const float* qp = sp + 3 * (ii * 128 + lane);
                const v2f px2 = {qp[0], qp[192]};
                const v2f py2 = {qp[1], qp[193]};
                const v2f pz2 = {qp[2], qp[194]};
#pragma unroll
                for (int j = 0; j < QPW; ++j) {
                    const v2f dx = pk_add(px2, nqx2[j]);
                    const v2f dy = pk_add(py2, nqy2[j]);
                    const v2f dz = pk_add(pz2, nqz2[j]);
                    const v2f d2 = pk_add(pk_add(pk_mul(dx, dx), pk_mul(dy, dy)),
                                          pk_mul(dz, dz));
                    unsigned long long m0 = __ballot(d2.x <= Tf[j]);
                    unsigned long long m1 = __ballot(d2.y <= Tf[j]);
                    // all m0 candidates (gb+c) < all m1 candidates (gb+64+c):
                    // popping m0 to exhaustion first keeps global ascending order.
                    while (m0 | m1) {
                        const bool lo = (m0 != 0);
                        const unsigned long long mm = lo ? m0 : m1;
                        const int c = (int)__builtin_ctzll(mm);
                        if (lo) m0 &= m0 - 1; else m1 &= m1 - 1;
                        const int b0 = __builtin_amdgcn_readlane(__float_as_int(d2.x), c);
                        const int b1 = __builtin_amdgcn_readlane(__float_as_int(d2.y), c);
                        const float dn = __int_as_float(lo ? b0 : b1);
                        const int cand = gb + (lo ? 0 : 64) + c;
                        // Self-guarding sorted insert (no-op if dn >= current max).
                        const unsigned long long sh = __ballot(ld[j] > dn);
                        const int p = sh ? (int)__builtin_ctzll(sh) : 64;
                        const int sld = dpp_shr1(__float_as_int(ld[j]));
                        const int sli = dpp_shr1(li[j]);
                        const int nld = sel_mask_i(sh, sld, __float_as_int(ld[j]));
                        const int nli = sel_mask_i(sh, sli, li[j]);
                        ld[j] = __int_as_float((lane == p) ? __float_as_int(dn) : nld);
                        li[j] = (lane == p) ? cand : nli;
                    }
                }
            }
            if (t + 1 < NT) {
                if (t + 2 < NT) { VW3; } else { VW0; }
            }
            cur = (cur == 2) ? 0 : cur + 1;
            pre = (pre == 2) ? 0 : pre + 1;
        }
    }

    // ---------------- Epilogue ----------------
    const size_t plane = (size_t)NQ * K;
#pragma unroll
    for (int j = 0; j < QPW; ++j) {
        const int q = q0 + j;
        if (lane < K) {
            const int idx = li[j];
            const float px = xb[idx * 3 + 0];
            const float py = xb[idx * 3 + 1];
            const float pz = xb[idx * 3 + 2];
            const size_t o = (((size_t)b * CHOUT + 0) * NQ + q) * K + lane;
            out[o]             = __fadd_rn(px, nqx[j]);   // == px - qx, exact
            out[o + plane]     = __fadd_rn(py, nqy[j]);
            out[o + 2 * plane] = __fadd_rn(pz, nqz[j]);
        }
        if (FUSED) {
            // feature channels 3..66: lane (s,h) pulls half-row h (128 B) of
            // point li[j]@lane s, scatters per-channel (2x128-B chunks/instr).
            const int s = lane & 31, h = lane >> 5;
            const int pidx = __shfl(li[j], s);
            const v4f* src = (const v4f*)(ft + ((size_t)b * NPTS + pidx) * NCH) + h * 8;
            v4f r[8];
#pragma unroll
            for (int k2 = 0; k2 < 8; ++k2) r[k2] = src[k2];
            float* ob = out + (((size_t)b * CHOUT + 3) * NQ + q) * K + s;
#pragma unroll
            for (int k2 = 0; k2 < 8; ++k2) {
                const int c0 = h * 32 + k2 * 4;
                ob[(size_t)(c0 + 0) * plane] = r[k2].x;
                ob[(size_t)(c0 + 1) * plane] = r[k2].y;
                ob[(size_t)(c0 + 2) * plane] = r[k2].z;
                ob[(size_t)(c0 + 3) * plane] = r[k2].w;
            }
        } else if (lane < K) {
            out_idx[((size_t)(b * NQ) + q) * K + lane] = li[j];
        }
    }
}

// ---------------------------------------------------------------------------
// Kernel T: features (B,C,N) -> featT (B,N,C). 64n x 64c tiles, v4f both
// sides, LDS [64][65] (2-way max, free). Runs inside the harness-fixed gap.
// ---------------------------------------------------------------------------
__global__ __launch_bounds__(256) void transpose_kernel(
    const float* __restrict__ f, float* __restrict__ ft)
{
    __shared__ float sm[64][65];   // 16.6 KB
    const int tid = threadIdx.x;
    const int nb  = blockIdx.x & 255;         // NPTS/64 tiles
    const int b   = blockIdx.x >> 8;
    const int n0  = nb * 64;
    const int w = tid >> 6, lane = tid & 63;
    const int r = lane >> 4, i = lane & 15;
    const float* fb = f + (size_t)b * NCH * NPTS;
#pragma unroll
    for (int g = 0; g < 4; ++g) {             // channels g*16 + w*4 + r
        const int c = g * 16 + w * 4 + r;
        const v4f v = *(const v4f*)(fb + (size_t)c * NPTS + n0 + 4 * i);
        sm[4 * i + 0][c] = v.x;
        sm[4 * i + 1][c] = v.y;
        sm[4 * i + 2][c] = v.z;
        sm[4 * i + 3][c] = v.w;
    }
    __syncthreads();
    float* ftb = ft + ((size_t)b * NPTS + n0) * NCH;
#pragma unroll
    for (int h = 0; h < 4; ++h) {             // rows n = h*16 + w*4 + r
        const int n = h * 16 + w * 4 + r;
        *(v4f*)(ftb + (size_t)n * NCH + 4 * i) = *(const v4f*)(&sm[n][4 * i]);
    }
}

// ---------------------------------------------------------------------------
// Fallback gather (R6 path) in case ws_size cannot hold featT.
// ---------------------------------------------------------------------------
__global__ __launch_bounds__(1024) void gather_kernel(
    const float* __restrict__ features,
    const int*   __restrict__ idx,
    float* __restrict__ out)
{
    __shared__ __align__(16) float row[NPTS];   // 64 KB

    const int tid  = threadIdx.x;
    const int half = blockIdx.x & 1;
    const int c    = (blockIdx.x >> 1) & 63;
    const int b    = blockIdx.x >> 7;

    const v4f* src = (const v4f*)(features + ((size_t)(b * NCH + c)) * NPTS);
    for (int k2 = tid; k2 < NPTS / 4; k2 += 1024) ((v4f*)row)[k2] = src[k2];
    __syncthreads();

    const size_t hofs = (size_t)half * (NQ * K / 2);
    const v4i* gi = (const v4i*)(idx + (size_t)b * NQ * K + hofs);
    v4f* dst = (v4f*)(out + ((size_t)(b * CHOUT + 3 + c)) * NQ * K + hofs);

    v4i cur = gi[tid];
#pragma unroll
    for (int it = 0; it < 16; ++it) {                  // NQ*K/8/1024 = 16
        v4i nxt;
        if (it < 15) nxt = gi[tid + (it + 1) * 1024];
        v4f o;
        o.x = row[cur.x]; o.y = row[cur.y]; o.z = row[cur.z]; o.w = row[cur.w];
        dst[tid + it * 1024] = o;
        cur = nxt;
    }
}

extern "C" void kernel_launch(void* const* d_in, const int* in_sizes, int n_in,
                              void* d_out, int out_size, void* d_ws, size_t ws_size,
                              hipStream_t stream) {
    const float* xyz      = (const float*)d_in[0];
    const float* new_xyz  = (const float*)d_in[1];
    const float* features = (const float*)d_in[2];
    float* out = (float*)d_out;

    const size_t ft_bytes = (size_t)NBATCH * NPTS * NCH * sizeof(float);  // 16.8 MB

    if (ws_size >= ft_bytes) {
        float* featT = (float*)d_ws;
        transpose_kernel<<<dim3(NBATCH * (NPTS / 64)), dim3(256), 0, stream>>>(features, featT);
        knn_kernel<true><<<dim3(NBATCH * (NQ / QPW)), dim3(64), 0, stream>>>(
            xyz, new_xyz, featT, nullptr, out);
    } else {
        int* ws_idx = (int*)d_ws;   // 2 MB
        knn_kernel<false><<<dim3(NBATCH * (NQ / QPW)), dim3(64), 0, stream>>>(
            xyz, new_xyz, nullptr, ws_idx, out);
        gather_kernel<<<dim3(NBATCH * NCH * 2), dim3(1024), 0, stream>>>(features, ws_idx, out);
    }
}